// Round 6
// baseline (3399.001 us; speedup 1.0000x reference)
//
#include <hip/hip_runtime.h>
#include <cstdint>
#include <cstddef>

#define B64 64
#define TDEC 20
#define VV 12000
#define EE 256
#define HH 512
#define DD 1024
#define RR 36

typedef __attribute__((ext_vector_type(8))) short bf16x8;
typedef __attribute__((ext_vector_type(4))) float f32x4;

__device__ __forceinline__ unsigned short f2b(float f) {
    unsigned u = __float_as_uint(f);
    unsigned r = (u + 0x7FFFu + ((u >> 16) & 1u)) >> 16;
    return (unsigned short)r;
}
__device__ __forceinline__ float b2f(unsigned short h) {
    return __uint_as_float(((unsigned)h) << 16);
}

// ---------------- sort (stable argsort desc by length) ----------------
__global__ void k_sort(const int* __restrict__ cap_len,
                       const int* __restrict__ captions,
                       int* __restrict__ sind, int* __restrict__ dec_i,
                       int* __restrict__ caps_s,
                       float* __restrict__ out_dec,
                       float* __restrict__ out_sind,
                       float* __restrict__ out_caps)
{
    int i = threadIdx.x;
    __shared__ int lens[B64];
    lens[i] = cap_len[i];
    __syncthreads();
    int li = lens[i];
    int rank = 0;
    for (int j = 0; j < B64; ++j) {
        int lj = lens[j];
        if (lj > li || (lj == li && j < i)) rank++;
    }
    sind[rank] = i;
    dec_i[rank] = li - 1;
    out_dec[rank] = (float)(li - 1);
    out_sind[rank] = (float)i;
    for (int t = 0; t < 21; ++t) {
        int tok = captions[i * 21 + t];
        caps_s[rank * 21 + t] = tok;
        if (t >= 1) out_caps[rank * 20 + (t - 1)] = (float)tok;
    }
}

// ---------------- init: hS bf16 [64][512], cS f32 [64][512] ----------------
__global__ void k_init(const float* __restrict__ h0, const int* __restrict__ sind,
                       unsigned short* __restrict__ hS, float* __restrict__ cS)
{
    int idx = blockIdx.x * blockDim.x + threadIdx.x;
    if (idx >= B64 * HH) return;
    int b = idx >> 9, p = idx & 511;
    float v = h0[sind[b] * HH + p];
    hS[idx] = f2b(v);
    cS[idx] = v;
}

// ---------------- gather sorted object proposals -> bf16 ----------------
__global__ void k_gobjs(const float* __restrict__ objs, const int* __restrict__ sind,
                        unsigned short* __restrict__ objs_b)
{
    int idx = blockIdx.x * blockDim.x + threadIdx.x;
    if (idx >= B64 * RR * DD) return;
    int b = idx / (RR * DD);
    int rest = idx - b * (RR * DD);
    objs_b[idx] = f2b(objs[(size_t)sind[b] * (RR * DD) + rest]);
}

// ---------------- gather embeddings for all (t,b) -> bf16 ----------------
__global__ void k_gA(const float* __restrict__ embW, const int* __restrict__ caps_s,
                     unsigned short* __restrict__ AembB)
{
    int idx = blockIdx.x * blockDim.x + threadIdx.x;
    if (idx >= TDEC * B64 * EE) return;
    int tb = idx >> 8, e = idx & 255;
    int t = tb >> 6, b = tb & 63;
    int tok = caps_s[b * 21 + t];
    AembB[idx] = f2b(embW[(size_t)tok * EE + e]);
}

// ---------------- weight conversions fused (grid-stride) ----------------
#define T_EMB  3072000
#define T_WIH  524288
#define T_RH   524288
#define T_WHT  131072
#define T_WRF  2097152
#define T_WHH  1048576
#define T_ALL  (T_EMB + T_WIH + T_RH + T_WHT + T_WRF + T_WHH)
__global__ void k_prep(const float* __restrict__ embW, const float* __restrict__ Wih,
                       const float* __restrict__ Whh, const float* __restrict__ rhW,
                       const float* __restrict__ whW,
                       unsigned short* __restrict__ embB, unsigned short* __restrict__ WihB,
                       unsigned short* __restrict__ rhW_b, unsigned short* __restrict__ whT,
                       unsigned short* __restrict__ WihRf, unsigned short* __restrict__ Whh_b)
{
    for (int idx = blockIdx.x * blockDim.x + threadIdx.x; idx < T_ALL;
         idx += gridDim.x * blockDim.x) {
        int i = idx;
        if (i < T_EMB) { embB[i] = f2b(embW[i]); continue; }
        i -= T_EMB;
        if (i < T_WIH) {        // WihB[ro][e] = Wih[ro][e], e<256
            int row = i >> 8, col = i & 255;
            WihB[i] = f2b(Wih[(size_t)row * 1280 + col]);
            continue;
        }
        i -= T_WIH;
        if (i < T_RH) { rhW_b[i] = f2b(rhW[i]); continue; }
        i -= T_RH;
        if (i < T_WHT) {        // whT[e][k] = whW[k][e]
            int e = i >> 9, k = i & 511;
            whT[i] = f2b(whW[(size_t)k * EE + e]);
            continue;
        }
        i -= T_WHT;
        if (i < T_WRF) {        // WihRf[ro][d] = Wih[ro][256+d]
            int row = i >> 10, d = i & 1023;
            WihRf[i] = f2b(Wih[(size_t)row * 1280 + 256 + d]);
            continue;
        }
        i -= T_WRF;
        Whh_b[i] = f2b(Whh[i]); // natural [2048][512]
    }
}

// ---------------- emb_sum partials + reduce (fp32 exact) ----------------
__global__ void k_embsum(const float* __restrict__ embW, float* __restrict__ partial)
{
    int e = threadIdx.x;
    int v0 = blockIdx.x * 50;
    float a = 0.0f;
    for (int v = v0; v < v0 + 50; ++v) a += embW[(size_t)v * EE + e];
    partial[blockIdx.x * EE + e] = a;
}
__global__ void k_embred(const float* __restrict__ partial, float* __restrict__ emb_sum)
{
    int e = threadIdx.x;
    float a = 0.0f;
    for (int j = 0; j < 240; ++j) a += partial[j * EE + e];
    emb_sum[e] = a;
}

// ---------------- pw[d] = emb_sum . wr_W[d,:] + V*wr_b[d] ----------------
__global__ void k_pwsum(const float* __restrict__ emb_sum, const float* __restrict__ wrW,
                        const float* __restrict__ wr_b, float* __restrict__ pw)
{
    __shared__ float es[EE];
    es[threadIdx.x] = emb_sum[threadIdx.x];
    __syncthreads();
    int d = blockIdx.x * 256 + threadIdx.x;
    float a = 0.0f;
    const float* row = wrW + (size_t)d * EE;
    for (int e = 0; e < EE; ++e) a = fmaf(es[e], row[e], a);
    pw[d] = a + 12000.0f * wr_b[d];
}

// ---------------- per-b: obj_sum -> s_wr, srb, sumv_wr, r_lin ----------
__global__ void k_objpre(const unsigned short* __restrict__ objs_b, const float* __restrict__ wrW,
                         const float* __restrict__ wr_b, const float* __restrict__ pw,
                         const float* __restrict__ rW, const float* __restrict__ r_b,
                         float* __restrict__ s_wr, float* __restrict__ srb,
                         float* __restrict__ sumv, float* __restrict__ r_lin)
{
    int b = blockIdx.x, tid = threadIdx.x;
    __shared__ float os[DD];
    __shared__ float red[256];
    const unsigned short* ob = objs_b + (size_t)b * RR * DD;
    for (int d = tid; d < DD; d += 256) {
        float a = 0.0f;
        for (int r = 0; r < RR; ++r) a += b2f(ob[r * DD + d]);
        os[d] = a;
    }
    __syncthreads();
    float a = 0.0f;
    for (int d = 0; d < DD; ++d) a = fmaf(os[d], wrW[(size_t)d * EE + tid], a);
    s_wr[b * EE + tid] = a;
    float p = 0.0f;
    for (int d = tid; d < DD; d += 256) p = fmaf(os[d], wr_b[d], p);
    red[tid] = p;
    __syncthreads();
    for (int s = 128; s > 0; s >>= 1) { if (tid < s) red[tid] += red[tid + s]; __syncthreads(); }
    if (tid == 0) srb[b] = red[0];
    if (tid < RR) {
        const unsigned short* row = ob + (size_t)tid * DD;
        float sv = 0.0f, rl = 0.0f;
        for (int d = 0; d < DD; ++d) { float x = b2f(row[d]); sv = fmaf(pw[d], x, sv); rl = fmaf(rW[d], x, rl); }
        sumv[b * RR + tid] = sv;
        r_lin[b * RR + tid] = rl + r_b[0];
    }
}

// ---------------- bf16 MFMA GEMM, fp32 out: C = A*B^T + bias1 + bias2 -------
__global__ __launch_bounds__(256) void k_bgemm(
    const unsigned short* __restrict__ A, int lda,
    const unsigned short* __restrict__ B, int ldb,
    float* __restrict__ C, int ldc, int K,
    const float* __restrict__ bias1, const float* __restrict__ bias2)
{
    int tid = threadIdx.x;
    int wv = tid >> 6, lane = tid & 63;
    int l15 = lane & 15, lg = lane >> 4;
    int m0 = blockIdx.x * 32 + (wv & 1) * 16;
    int n0 = blockIdx.y * 32 + (wv >> 1) * 16;
    const unsigned short* Ar = A + (size_t)(m0 + l15) * lda + lg * 8;
    const unsigned short* Br = B + (size_t)(n0 + l15) * ldb + lg * 8;
    f32x4 acc0 = {0.f, 0.f, 0.f, 0.f}, acc1 = {0.f, 0.f, 0.f, 0.f};
#pragma unroll 4
    for (int k0 = 0; k0 < K; k0 += 64) {
        bf16x8 a0 = *(const bf16x8*)(Ar + k0);
        bf16x8 b0 = *(const bf16x8*)(Br + k0);
        bf16x8 a1 = *(const bf16x8*)(Ar + k0 + 32);
        bf16x8 b1 = *(const bf16x8*)(Br + k0 + 32);
        acc0 = __builtin_amdgcn_mfma_f32_16x16x32_bf16(a0, b0, acc0, 0, 0, 0);
        acc1 = __builtin_amdgcn_mfma_f32_16x16x32_bf16(a1, b1, acc1, 0, 0, 0);
    }
    int n = n0 + l15;
    float badd = 0.0f;
    if (bias1) badd += bias1[n];
    if (bias2) badd += bias2[n];
#pragma unroll
    for (int r = 0; r < 4; ++r) {
        int m = m0 + 4 * lg + r;
        C[(size_t)m * ldc + n] = acc0[r] + acc1[r] + badd;
    }
}

// ---------------- bf16 MFMA GEMM, bf16 out (rh_b16) ---------------
__global__ __launch_bounds__(256) void k_bgemm16(
    const unsigned short* __restrict__ A, int lda,
    const unsigned short* __restrict__ B, int ldb,
    unsigned short* __restrict__ C, int ldc, int K,
    const float* __restrict__ bias1)
{
    int tid = threadIdx.x;
    int wv = tid >> 6, lane = tid & 63;
    int l15 = lane & 15, lg = lane >> 4;
    int m0 = blockIdx.x * 32 + (wv & 1) * 16;
    int n0 = blockIdx.y * 32 + (wv >> 1) * 16;
    const unsigned short* Ar = A + (size_t)(m0 + l15) * lda + lg * 8;
    const unsigned short* Br = B + (size_t)(n0 + l15) * ldb + lg * 8;
    f32x4 acc0 = {0.f, 0.f, 0.f, 0.f}, acc1 = {0.f, 0.f, 0.f, 0.f};
#pragma unroll 4
    for (int k0 = 0; k0 < K; k0 += 64) {
        bf16x8 a0 = *(const bf16x8*)(Ar + k0);
        bf16x8 b0 = *(const bf16x8*)(Br + k0);
        bf16x8 a1 = *(const bf16x8*)(Ar + k0 + 32);
        bf16x8 b1 = *(const bf16x8*)(Br + k0 + 32);
        acc0 = __builtin_amdgcn_mfma_f32_16x16x32_bf16(a0, b0, acc0, 0, 0, 0);
        acc1 = __builtin_amdgcn_mfma_f32_16x16x32_bf16(a1, b1, acc1, 0, 0, 0);
    }
    int n = n0 + l15;
    float badd = bias1 ? bias1[n] : 0.0f;
#pragma unroll
    for (int r = 0; r < 4; ++r) {
        int m = m0 + 4 * lg + r;
        C[(size_t)m * ldc + n] = f2b(acc0[r] + acc1[r] + badd);
    }
}

// ---------------- OP2 GEMM: objs_b @ WihRf^T -> OP2[b][m][r] bf16 ----
__global__ __launch_bounds__(256) void k_opgemm(
    const unsigned short* __restrict__ A,      // objs_b [2304][1024]
    const unsigned short* __restrict__ WihRf,  // [2048][1024]
    unsigned short* __restrict__ OP2)          // [64][2048][36]
{
    int tid = threadIdx.x;
    int wv = tid >> 6, lane = tid & 63;
    int l15 = lane & 15, lg = lane >> 4;
    int m0 = blockIdx.x * 32 + (wv & 1) * 16;
    int n0 = blockIdx.y * 32 + (wv >> 1) * 16;
    const unsigned short* Ar = A + (size_t)(m0 + l15) * 1024 + lg * 8;
    const unsigned short* Br = WihRf + (size_t)(n0 + l15) * 1024 + lg * 8;
    f32x4 acc0 = {0.f, 0.f, 0.f, 0.f}, acc1 = {0.f, 0.f, 0.f, 0.f};
#pragma unroll 4
    for (int k0 = 0; k0 < 1024; k0 += 64) {
        bf16x8 a0 = *(const bf16x8*)(Ar + k0);
        bf16x8 b0 = *(const bf16x8*)(Br + k0);
        bf16x8 a1 = *(const bf16x8*)(Ar + k0 + 32);
        bf16x8 b1 = *(const bf16x8*)(Br + k0 + 32);
        acc0 = __builtin_amdgcn_mfma_f32_16x16x32_bf16(a0, b0, acc0, 0, 0, 0);
        acc1 = __builtin_amdgcn_mfma_f32_16x16x32_bf16(a1, b1, acc1, 0, 0, 0);
    }
    int n = n0 + l15;
#pragma unroll
    for (int r = 0; r < 4; ++r) {
        int m = m0 + 4 * lg + r;              // row of objs (b*36 + rr)
        int b = m / 36, rr = m - b * 36;
        OP2[((size_t)b * 2048 + n) * 36 + rr] = f2b(acc0[r] + acc1[r]);
    }
}

// ============ per-b-pair recurrence: 32 blocks x 512, ZERO grid sync ========
__global__ __launch_bounds__(512) void k_recur(
    const unsigned short* __restrict__ Whh_b,   // [2048][512]
    const unsigned short* __restrict__ OP2,     // [64][2048][36]
    const float* __restrict__ ge,               // [1280][2048]
    const unsigned short* __restrict__ hS,      // [64][512] init
    const float* __restrict__ cS,               // [64][512] init
    const int* __restrict__ dec_i,
    const unsigned short* __restrict__ rh_b16,  // [2304+16][512]
    const float* __restrict__ sumv, const float* __restrict__ r_lin,
    const unsigned short* __restrict__ whT,     // [256][512]
    const float* __restrict__ wh_b, const float* __restrict__ wW, const float* __restrict__ w_b,
    const float* __restrict__ emb_sum,
    const float* __restrict__ s_wr, const float* __restrict__ srb,
    unsigned short* __restrict__ Gb, float* __restrict__ g0,
    float* __restrict__ attn_out)
{
    const int tid = threadIdx.x;
    const int blk = blockIdx.x;                 // 0..31
    const int b0 = 2 * blk;
    const int wv = tid >> 6, lane = tid & 63;
    const int l15 = lane & 15, lg = lane >> 4;
    const int bsel = l15 >> 3;                  // which b of the pair (via MFMA col)
    const int dec0 = dec_i[b0];                 // >= dec1 (sorted desc)
    const int dec1 = dec_i[b0 + 1];

    __shared__ __align__(16) unsigned short hsh[2][512];
    __shared__ __align__(16) float csh[2][512];
    __shared__ __align__(16) float gsh[2][2048];
    __shared__ __align__(16) float ush[2][256];
    __shared__ float rvsh[2][40];
    __shared__ float rash[2][36];
    __shared__ float red1[512], red2[512];

    // ---- init LDS state ----
    for (int i = tid; i < 1024; i += 512) {
        int bb = i >> 9, p = i & 511;
        hsh[bb][p] = hS[(size_t)(b0 + bb) * 512 + p];
        csh[bb][p] = cS[(size_t)(b0 + bb) * 512 + p];
    }
    if (tid < 72) rash[tid / 36][tid % 36] = 0.0f;
    __syncthreads();

    int t = 0;
    for (; t < TDEC; ++t) {
        if (t >= dec0) break;
        const bool act1 = (t < dec1);

        // ======== GEMV-1: gates = Whh @ h  (B = h replicated per pair-half) ==
        for (int j = 0; j < 16; ++j) {
            int mt = (wv + 8 * j) * 16;
            const unsigned short* Ar = Whh_b + (size_t)(mt + l15) * 512 + lg * 8;
            f32x4 acc0 = {0.f, 0.f, 0.f, 0.f}, acc1 = {0.f, 0.f, 0.f, 0.f};
#pragma unroll
            for (int k0 = 0; k0 < 512; k0 += 64) {
                bf16x8 a0 = *(const bf16x8*)(Ar + k0);
                bf16x8 a1 = *(const bf16x8*)(Ar + k0 + 32);
                bf16x8 h0v = *(const bf16x8*)(&hsh[bsel][k0 + lg * 8]);
                bf16x8 h1v = *(const bf16x8*)(&hsh[bsel][k0 + 32 + lg * 8]);
                acc0 = __builtin_amdgcn_mfma_f32_16x16x32_bf16(a0, h0v, acc0, 0, 0, 0);
                acc1 = __builtin_amdgcn_mfma_f32_16x16x32_bf16(a1, h1v, acc1, 0, 0, 0);
            }
            if ((l15 & 7) == 0) {
                float4 s;
                s.x = acc0[0] + acc1[0]; s.y = acc0[1] + acc1[1];
                s.z = acc0[2] + acc1[2]; s.w = acc0[3] + acc1[3];
                *(float4*)&gsh[bsel][mt + 4 * lg] = s;
            }
        }
        __syncthreads();

        // ======== gates epilogue: OP2·ra + ge + activations + h/c update =====
        {
            int bb = tid >> 8, i0 = tid & 255;
            int bq = b0 + bb;
            bool actb = (bb == 0) ? true : act1;
            const float* geb = ge + ((size_t)t * B64 + bq) * 2048;
#pragma unroll
            for (int half = 0; half < 2; ++half) {
                int hp = i0 + half * 256;
                float gv[4];
#pragma unroll
                for (int g = 0; g < 4; ++g) {
                    int m = g * 512 + hp;
                    const unsigned short* op = OP2 + ((size_t)bq * 2048 + m) * 36;
                    bf16x8 o0 = *(const bf16x8*)(op);
                    bf16x8 o1 = *(const bf16x8*)(op + 8);
                    bf16x8 o2 = *(const bf16x8*)(op + 16);
                    bf16x8 o3 = *(const bf16x8*)(op + 24);
                    ushort4 o4 = *(const ushort4*)(op + 32);
                    float s = 0.0f;
#pragma unroll
                    for (int r = 0; r < 8; ++r) {
                        s = fmaf(rash[bb][r], b2f((unsigned short)o0[r]), s);
                        s = fmaf(rash[bb][8 + r], b2f((unsigned short)o1[r]), s);
                        s = fmaf(rash[bb][16 + r], b2f((unsigned short)o2[r]), s);
                        s = fmaf(rash[bb][24 + r], b2f((unsigned short)o3[r]), s);
                    }
                    s = fmaf(rash[bb][32], b2f(o4.x), s);
                    s = fmaf(rash[bb][33], b2f(o4.y), s);
                    s = fmaf(rash[bb][34], b2f(o4.z), s);
                    s = fmaf(rash[bb][35], b2f(o4.w), s);
                    gv[g] = gsh[bb][m] + s + geb[m];
                }
                float ii = 1.0f / (1.0f + expf(-gv[0]));
                float ff = 1.0f / (1.0f + expf(-gv[1]));
                float g2 = tanhf(gv[2]);
                float oo = 1.0f / (1.0f + expf(-gv[3]));
                float cold = csh[bb][hp];
                float cn = ff * cold + ii * g2;
                float hn = oo * tanhf(cn);
                if (actb) {
                    csh[bb][hp] = cn;
                    hsh[bb][hp] = f2b(hn);
                }
            }
        }
        __syncthreads();

        // ======== GEMV-2: u (whT, 16 tiles) + rvec (rh pair-concat, 5 tiles) =
        for (int tile = wv; tile < 21; tile += 8) {
            const unsigned short* Ar;
            if (tile < 16)
                Ar = whT + (size_t)(tile * 16 + l15) * 512 + lg * 8;
            else
                Ar = rh_b16 + (size_t)(blk * 72 + (tile - 16) * 16 + l15) * 512 + lg * 8;
            f32x4 acc0 = {0.f, 0.f, 0.f, 0.f}, acc1 = {0.f, 0.f, 0.f, 0.f};
#pragma unroll
            for (int k0 = 0; k0 < 512; k0 += 64) {
                bf16x8 a0 = *(const bf16x8*)(Ar + k0);
                bf16x8 a1 = *(const bf16x8*)(Ar + k0 + 32);
                bf16x8 h0v = *(const bf16x8*)(&hsh[bsel][k0 + lg * 8]);
                bf16x8 h1v = *(const bf16x8*)(&hsh[bsel][k0 + 32 + lg * 8]);
                acc0 = __builtin_amdgcn_mfma_f32_16x16x32_bf16(a0, h0v, acc0, 0, 0, 0);
                acc1 = __builtin_amdgcn_mfma_f32_16x16x32_bf16(a1, h1v, acc1, 0, 0, 0);
            }
            if (tile < 16) {
                if ((l15 & 7) == 0) {
                    float4 s;
                    s.x = acc0[0] + acc1[0]; s.y = acc0[1] + acc1[1];
                    s.z = acc0[2] + acc1[2]; s.w = acc0[3] + acc1[3];
                    *(float4*)&ush[bsel][tile * 16 + 4 * lg] = s;
                }
            } else {
#pragma unroll
                for (int r = 0; r < 4; ++r) {
                    int q = (tile - 16) * 16 + 4 * lg + r;
                    float v = acc0[r] + acc1[r];
                    if (l15 == 0 && q < 36) rvsh[0][q] = v;
                    if (l15 == 8 && q >= 36 && q < 72) rvsh[1][q - 36] = v;
                }
            }
        }
        __syncthreads();

        // ======== attention epilogue (both b's in parallel halves) ===========
        {
            int bb = tid >> 8, i = tid & 255;
            int bq = b0 + bb;
            red1[tid] = b2f(hsh[bb][2 * i]) * wh_b[2 * i]
                      + b2f(hsh[bb][2 * i + 1]) * wh_b[2 * i + 1];
            float ut = ush[bb][i] + wW[i];
            Gb[((size_t)t * B64 + bq) * EE + i] = f2b(ut + s_wr[bq * EE + i]);
            red2[tid] = ut * emb_sum[i];
        }
        __syncthreads();
        for (int s = 128; s > 0; s >>= 1) {
            if ((tid & 255) < s) {
                red1[tid] += red1[tid + s];
                red2[tid] += red2[tid + s];
            }
            __syncthreads();
        }
        if (wv < 2) {
            int bb = wv;
            int bq = b0 + bb;
            bool actb = (bb == 0) ? true : act1;
            float hwb = red1[bb * 256] + w_b[0];
            float wtsum = red2[bb * 256] + 12000.0f * hwb;
            float rv = (lane < RR) ? (rvsh[bb][lane] + r_lin[bq * RR + lane]) : 0.0f;
            float lgv = (lane < RR) ? (wtsum + sumv[bq * RR + lane] + rv) : -3.0e38f;
            float mx = lgv;
#pragma unroll
            for (int o = 32; o > 0; o >>= 1) mx = fmaxf(mx, __shfl_xor(mx, o));
            float ev = (lane < RR) ? __expf(lgv - mx) : 0.0f;
            float sm = ev, rvs = rv;
#pragma unroll
            for (int o = 32; o > 0; o >>= 1) { sm += __shfl_xor(sm, o); rvs += __shfl_xor(rvs, o); }
            if (lane < RR) {
                float ra = ev / sm;
                attn_out[((size_t)bq * TDEC + t) * RR + lane] = actb ? ra : 0.0f;
                if (actb) rash[bb][lane] = ra;
            }
            if (lane == 0) g0[t * B64 + bq] = hwb + srb[bq] + rvs;
        }
        __syncthreads();
    }
    // ---- tail: zero remaining attention rows for both b's ----
    int t_end = t;
    int nrem = (TDEC - t_end) * 72;
    for (int idx = tid; idx < nrem; idx += 512) {
        int tt = idx / 72, rem = idx - tt * 72;
        int bbz = rem / 36, r = rem - bbz * 36;
        attn_out[((size_t)(b0 + bbz) * TDEC + (t_end + tt)) * RR + r] = 0.0f;
    }
}

// ---------------- final predictions MFMA + LDS-staged coalesced stores ------
__global__ __launch_bounds__(256) void k_preds(
    const unsigned short* __restrict__ Gb, const unsigned short* __restrict__ embB,
    const float* __restrict__ g0, const int* __restrict__ dec_i,
    float* __restrict__ out)
{
    __shared__ float outs[64 * 132];
    __shared__ float sadd[64];
    __shared__ int sact[64];
    int tid = threadIdx.x;
    int wv = tid >> 6, lane = tid & 63;
    int l15 = lane & 15, lg = lane >> 4;
    int tq = blockIdx.x;
    int n00 = blockIdx.y * 128;
    int m0w = wv * 16;
    if (tid < 64) { sadd[tid] = g0[tq * 64 + tid]; sact[tid] = dec_i[tid] > tq; }
    bf16x8 afr[8];
    const unsigned short* Ar = Gb + (size_t)(tq * 64 + m0w + l15) * EE + lg * 8;
#pragma unroll
    for (int k = 0; k < 8; ++k) afr[k] = *(const bf16x8*)(Ar + k * 32);
    const bf16x8 zb = {0, 0, 0, 0, 0, 0, 0, 0};
#pragma unroll
    for (int nf = 0; nf < 8; ++nf) {
        int nb = n00 + nf * 16 + l15;
        bool bok = nb < VV;
        const unsigned short* Br = embB + (size_t)nb * EE + lg * 8;
        f32x4 acc = {0.f, 0.f, 0.f, 0.f};
#pragma unroll
        for (int k = 0; k < 8; ++k) {
            bf16x8 bb8 = bok ? *(const bf16x8*)(Br + k * 32) : zb;
            acc = __builtin_amdgcn_mfma_f32_16x16x32_bf16(afr[k], bb8, acc, 0, 0, 0);
        }
#pragma unroll
        for (int r = 0; r < 4; ++r)
            outs[(m0w + 4 * lg + r) * 132 + nf * 16 + l15] = acc[r];
    }
    __syncthreads();
#pragma unroll
    for (int it = 0; it < 8; ++it) {
        int row = it * 8 + (tid >> 5);
        int c = (tid & 31) * 4;
        if (n00 + c < VV) {
            float add = sadd[row];
            bool a = sact[row] != 0;
            const float* src = outs + row * 132 + c;
            float4 v;
            v.x = a ? src[0] + add : 0.0f;
            v.y = a ? src[1] + add : 0.0f;
            v.z = a ? src[2] + add : 0.0f;
            v.w = a ? src[3] + add : 0.0f;
            *(float4*)(out + ((size_t)row * TDEC + tq) * VV + n00 + c) = v;
        }
    }
}

extern "C" void kernel_launch(void* const* d_in, const int* in_sizes, int n_in,
                              void* d_out, int out_size, void* d_ws, size_t ws_size,
                              hipStream_t stream)
{
    const float* h0      = (const float*)d_in[0];
    const float* objs    = (const float*)d_in[1];
    const int*   caps    = (const int*)d_in[2];
    const int*   cap_len = (const int*)d_in[3];
    const float* embW    = (const float*)d_in[4];
    const float* whW     = (const float*)d_in[5];
    const float* wh_b    = (const float*)d_in[6];
    const float* wrW     = (const float*)d_in[7];
    const float* wr_b    = (const float*)d_in[8];
    const float* rhW     = (const float*)d_in[9];
    const float* rh_b    = (const float*)d_in[10];
    const float* wW      = (const float*)d_in[11];
    const float* w_b     = (const float*)d_in[12];
    const float* rW      = (const float*)d_in[13];
    const float* r_b     = (const float*)d_in[14];
    const float* Wih     = (const float*)d_in[15];
    const float* Whh     = (const float*)d_in[16];
    const float* bih     = (const float*)d_in[17];
    const float* bhh     = (const float*)d_in[18];

    float* out = (float*)d_out;
    float* out_pred = out;                      // 64*20*12000
    float* out_attn = out + 15360000;           // 64*20*36
    float* out_caps = out + 15406080;           // 64*20
    float* out_dec  = out + 15407360;           // 64
    float* out_sind = out + 15407424;           // 64

    float* f = (float*)d_ws;
    size_t o = 0;
    float* ge      = f + o; o += (size_t)TDEC * B64 * 2048;  // 2,621,440
    float* g0      = f + o; o += TDEC * B64;
    float* embpart = f + o; o += 240 * EE;
    float* emb_sum = f + o; o += EE;
    float* pw      = f + o; o += DD;
    float* sumv    = f + o; o += B64 * RR;
    float* r_lin   = f + o; o += B64 * RR;
    float* s_wr    = f + o; o += B64 * EE;
    float* srb     = f + o; o += B64;
    float* cS      = f + o; o += (size_t)B64 * HH;           // 32,768
    o = (o + 3) & ~(size_t)3;
    unsigned short* us = (unsigned short*)(f + o);
    size_t uo = 0;
    unsigned short* objs_b = us + uo; uo += (size_t)B64 * RR * DD;       // 2,359,296
    unsigned short* AembB  = us + uo; uo += (size_t)TDEC * B64 * EE;     // 327,680
    unsigned short* embB   = us + uo; uo += (size_t)VV * EE;             // 3,072,000
    unsigned short* WihB   = us + uo; uo += (size_t)2048 * EE;           // 524,288
    unsigned short* whT    = us + uo; uo += (size_t)EE * HH;             // 131,072
    unsigned short* rhW_b  = us + uo; uo += (size_t)HH * DD;             // 524,288
    unsigned short* WihRf  = us + uo; uo += (size_t)2048 * DD;           // 2,097,152
    unsigned short* Whh_b  = us + uo; uo += (size_t)2048 * HH;           // 1,048,576
    unsigned short* Gb     = us + uo; uo += (size_t)TDEC * B64 * EE;     // 327,680
    unsigned short* rh_b16 = us + uo; uo += (size_t)(B64 * RR + 16) * HH;// 1,187,840
    unsigned short* OP2    = us + uo; uo += (size_t)B64 * 2048 * RR;     // 4,718,592
    unsigned short* hS     = us + uo; uo += (size_t)B64 * HH;            // 32,768
    int* ibase  = (int*)(us + uo);
    int* sind   = ibase;
    int* dec_i  = ibase + 64;
    int* caps_s = ibase + 128;

    k_sort<<<1, 64, 0, stream>>>(cap_len, caps, sind, dec_i, caps_s, out_dec, out_sind, out_caps);
    k_init<<<128, 256, 0, stream>>>(h0, sind, hS, cS);
    k_gobjs<<<9216, 256, 0, stream>>>(objs, sind, objs_b);
    k_gA<<<1280, 256, 0, stream>>>(embW, caps_s, AembB);
    k_prep<<<8192, 256, 0, stream>>>(embW, Wih, Whh, rhW, whW, embB, WihB, rhW_b, whT, WihRf, Whh_b);
    k_embsum<<<240, 256, 0, stream>>>(embW, embpart);
    k_embred<<<1, 256, 0, stream>>>(embpart, emb_sum);
    k_pwsum<<<4, 256, 0, stream>>>(emb_sum, wrW, wr_b, pw);
    k_objpre<<<64, 256, 0, stream>>>(objs_b, wrW, wr_b, pw, rW, r_b, s_wr, srb, sumv, r_lin);
    {
        dim3 g1(72, 16);   // rh_b16: M=2304, N=512, K=1024
        k_bgemm16<<<g1, 256, 0, stream>>>(objs_b, DD, rhW_b, DD, rh_b16, HH, DD, rh_b);
        dim3 g2(40, 64);   // ge: M=1280, N=2048, K=256
        k_bgemm<<<g2, 256, 0, stream>>>(AembB, EE, WihB, EE, ge, 2048, EE, bih, bhh);
        dim3 g3(72, 64);   // OP2: M=2304, N=2048, K=1024
        k_opgemm<<<g3, 256, 0, stream>>>(objs_b, WihRf, OP2);
    }
    k_recur<<<32, 512, 0, stream>>>(Whh_b, OP2, ge, hS, cS, dec_i, rh_b16,
                                    sumv, r_lin, whT, wh_b, wW, w_b, emb_sum,
                                    s_wr, srb, Gb, g0, out_attn);
    {
        dim3 g4(20, 94);
        k_preds<<<g4, 256, 0, stream>>>(Gb, embB, g0, dec_i, out_pred);
    }
}